// Round 2
// baseline (3592.867 us; speedup 1.0000x reference)
//
#include <hip/hip_runtime.h>

// CRF forward log-partition (log Z) per batch element. L = 128 fixed.
// logits [B,S,L] f32, transitions [L,L] f32, lens [B] int32, out [B] f32.
//
// Recurrence (log-semiring mat-vec):
//   alpha_{t+1}[i] = logit_t[i] + mu + log( sum_j expT[i][j] * w_t[j] ),
//   w_t[j] = exp(alpha_t[j] - mu),  mu = alpha_{t-1}[0]  (lagged normalizer).
// The lagged mu keeps |alpha - mu| <= ~20 (alpha spread ~8 + one-step growth),
// so exp() stays in f32 range with no per-step max reduction.
//
// One block (512 threads) per batch element:
//   thread tid: row r = tid>>2, quarter h = tid&3 owns expT[r][h*32 .. h*32+31]
//   in 8 float4 registers (statically indexed). Per step: 8 ds_read_b128 of the
//   shared w vector (broadcast, bank-rotated), 32 FMAs, 2 shfl_xor to combine
//   the 4 quarter-sums (adjacent lanes, same wave), ONE barrier (double-
//   buffered wlds/mred). Logit loads software-pipelined 1 step ahead.

constexpr int L = 128;

__global__ __launch_bounds__(512, 2) void crf_fwd_kernel(
    const float* __restrict__ logits,
    const float* __restrict__ trans,
    const int* __restrict__ lens,
    float* __restrict__ out,
    int S)
{
    const int b   = blockIdx.x;
    const int tid = threadIdx.x;   // 0..511
    const int r   = tid >> 2;      // output row 0..127
    const int h   = tid & 3;       // j-quarter 0..3

    __shared__ float wlds[2][L];   // w vector, double-buffered
    __shared__ float mred[2];      // lagged normalizer channel

    // ---- one-time: expT quarter-row into registers ----
    float4 row[8];
    {
        const float4* tq = reinterpret_cast<const float4*>(trans + r * L + h * 32);
#pragma unroll
        for (int k = 0; k < 8; ++k) {
            float4 v = tq[k];
            row[k] = make_float4(__expf(v.x), __expf(v.y), __expf(v.z), __expf(v.w));
        }
    }

    const int len  = lens[b];          // >= 1 guaranteed
    const int tmax = len - 1;
    const float* lpr = logits + (size_t)b * (size_t)S * L + r;

    // ---- init: alpha_1[r] = logit_0[r] + T[r][0]  (alpha_0 = e_BOS) ----
    {
        float t_r0 = trans[r * L];
        float lg0  = lpr[0];
        float a1   = lg0 + t_r0;
        if (h == 0)   wlds[0][r] = __expf(a1);   // mu_1 = 0
        if (tid == 0) mred[0]    = a1;           // mu_2 = alpha_1[0]
    }
    float mu_cur  = 0.0f;
    float lg_next = lpr[(size_t)(tmax > 0 ? 1 : 0) * L];   // logit_1 prefetch

    __syncthreads();

    int p = 0;
    for (int t = 1; t <= tmax; ++t) {
        float lg_t   = lg_next;
        lg_next      = lpr[(size_t)min(t + 1, tmax) * L];  // prefetch t+1 (clamped)
        float mu_nxt = mred[p];                            // alpha_t[0]

        // ---- quarter dot: sum_j expT[r][j] * w[j], j in h*32..h*32+31 ----
        const float4* w4 = reinterpret_cast<const float4*>(wlds[p]);
        float4 s4 = make_float4(0.f, 0.f, 0.f, 0.f);
#pragma unroll
        for (int k = 0; k < 8; ++k) {
            int kk = (k + 2 * h) & 7;      // rotate per-quarter: 4 distinct bank
            float4 w = w4[h * 8 + kk];     // groups per instr -> conflict-free
            s4.x = fmaf(row[kk].x, w.x, s4.x);
            s4.y = fmaf(row[kk].y, w.y, s4.y);
            s4.z = fmaf(row[kk].z, w.z, s4.z);
            s4.w = fmaf(row[kk].w, w.w, s4.w);
        }
        float s = (s4.x + s4.y) + (s4.z + s4.w);
        s += __shfl_xor(s, 1, 64);         // combine 4 quarter-sums:
        s += __shfl_xor(s, 2, 64);         // lanes r*4+h, h=0..3 (same wave)

        float alpha = lg_t + mu_cur + __logf(s);    // alpha_{t+1}[r]
        float w_new = __expf(alpha - mu_nxt);
        if (h == 0)   wlds[p ^ 1][r] = w_new;
        if (tid == 0) mred[p ^ 1]    = alpha;
        mu_cur = mu_nxt;
        p ^= 1;
        __syncthreads();
    }

    // ---- logZ = mu_cur + log( sum_j w_final[j] ) ----
    if (tid < 32) {
        float4 v = reinterpret_cast<const float4*>(wlds[p])[tid];
        float e  = (v.x + v.y) + (v.z + v.w);
#pragma unroll
        for (int off = 16; off >= 1; off >>= 1)
            e += __shfl_xor(e, off, 64);
        if (tid == 0) out[b] = mu_cur + __logf(e);
    }
}

extern "C" void kernel_launch(void* const* d_in, const int* in_sizes, int n_in,
                              void* d_out, int out_size, void* d_ws, size_t ws_size,
                              hipStream_t stream)
{
    const float* logits = (const float*)d_in[0];
    const float* trans  = (const float*)d_in[1];
    const int*   lens   = (const int*)d_in[2];
    float*       out    = (float*)d_out;

    const int B = in_sizes[2];                // lens element count
    const int S = in_sizes[0] / (B * L);      // logits = B*S*L

    crf_fwd_kernel<<<B, 512, 0, stream>>>(logits, trans, lens, out, S);
}

// Round 7
// 415.507 us; speedup vs baseline: 8.6470x; 8.6470x over previous
//
#include <hip/hip_runtime.h>

// CRF forward log-partition (log Z) per batch element. L = 128 fixed.
// logits [B,S,L] f32, transitions [L,L] f32, lens [B] int32, out [B] f32.
//
// Recurrence (log-semiring mat-vec):
//   alpha_{t+1}[i] = logit_t[i] + mu + log( sum_j expT[i][j] * w_t[j] ),
//   w_t[j] = exp(alpha_t[j] - mu),  mu = alpha_{t-1}[0]  (lagged normalizer).
// Lagged mu keeps |alpha - mu| small (verified: absmax 0.0 in R2), so no
// per-step max reduction is needed.
//
// One block (512 threads) per batch element:
//   thread tid: row r = tid>>2, quarter h = tid&3 owns expT[r][h*32..h*32+31]
//   in 8 float4 registers -- ALL indexing compile-time static (rule #20:
//   runtime-indexed reg arrays spill to scratch; that was R2's 6x regression).
// Bank conflicts are avoided by PADDING the shared w vector instead: each
// 32-float quarter padded to 36 floats, so the 4 broadcast read addresses per
// ds_read_b128 land in 4 disjoint bank groups (dword 36h+4k -> bank 4h+4k).
// Per step: 8 ds_read_b128 (broadcast, conflict-free), 32 v_fmac, 2 shfl_xor,
// ONE barrier (double-buffered). Logit loads software-pipelined 1 step ahead.

constexpr int L = 128;
constexpr int QPAD = 36;           // padded quarter stride (floats)

__global__ __launch_bounds__(512, 2) void crf_fwd_kernel(
    const float* __restrict__ logits,
    const float* __restrict__ trans,
    const int* __restrict__ lens,
    float* __restrict__ out,
    int S)
{
    const int b   = blockIdx.x;
    const int tid = threadIdx.x;   // 0..511
    const int r   = tid >> 2;      // output row 0..127
    const int h   = tid & 3;       // j-quarter 0..3

    __shared__ float wlds[2][4 * QPAD];   // w vector, padded, double-buffered
    __shared__ float mred[2];             // lagged normalizer channel

    // ---- one-time: expT quarter-row into registers (static indexing) ----
    float4 row[8];
    {
        const float4* tq = reinterpret_cast<const float4*>(trans + r * L + h * 32);
#pragma unroll
        for (int k = 0; k < 8; ++k) {
            float4 v = tq[k];
            row[k] = make_float4(__expf(v.x), __expf(v.y), __expf(v.z), __expf(v.w));
        }
    }

    const int len  = lens[b];          // >= 1 guaranteed
    const int tmax = len - 1;
    const float* lpr = logits + (size_t)b * (size_t)S * L + r;

    // ---- init: alpha_1[r] = logit_0[r] + T[r][0]  (alpha_0 = e_BOS) ----
    {
        float t_r0 = trans[r * L];
        float lg0  = lpr[0];
        float a1   = lg0 + t_r0;
        if (h == 0)   wlds[0][(r >> 5) * QPAD + (r & 31)] = __expf(a1); // mu_1 = 0
        if (tid == 0) mred[0] = a1;                                     // mu_2
    }
    float mu_cur  = 0.0f;
    float lg_next = lpr[(size_t)(tmax > 0 ? 1 : 0) * L];   // logit_1 prefetch

    __syncthreads();

    int p = 0;
    for (int t = 1; t <= tmax; ++t) {
        float lg_t   = lg_next;
        lg_next      = lpr[(size_t)min(t + 1, tmax) * L];  // prefetch t+1
        float mu_nxt = mred[p];                            // alpha_t[0]

        // ---- quarter dot: sum_j expT[r][j] * w[j], j in h*32..h*32+31 ----
        const float4* w4 = reinterpret_cast<const float4*>(wlds[p]) + h * (QPAD / 4);
        float4 s4 = make_float4(0.f, 0.f, 0.f, 0.f);
#pragma unroll
        for (int k = 0; k < 8; ++k) {          // static k: row[] stays in VGPRs
            float4 w = w4[k];
            s4.x = fmaf(row[k].x, w.x, s4.x);
            s4.y = fmaf(row[k].y, w.y, s4.y);
            s4.z = fmaf(row[k].z, w.z, s4.z);
            s4.w = fmaf(row[k].w, w.w, s4.w);
        }
        float s = (s4.x + s4.y) + (s4.z + s4.w);
        s += __shfl_xor(s, 1, 64);             // combine 4 quarter-sums
        s += __shfl_xor(s, 2, 64);             // (lanes r*4+h, same wave)

        float alpha = lg_t + mu_cur + __logf(s);    // alpha_{t+1}[r]
        float w_new = __expf(alpha - mu_nxt);
        if (h == 0)   wlds[p ^ 1][(r >> 5) * QPAD + (r & 31)] = w_new;
        if (tid == 0) mred[p ^ 1] = alpha;
        mu_cur = mu_nxt;
        p ^= 1;
        __syncthreads();
    }

    // ---- logZ = mu_cur + log( sum_j w_final[j] ) ----
    if (tid < 32) {
        const float4* wf = reinterpret_cast<const float4*>(wlds[p]);
        float4 v = wf[(tid >> 3) * (QPAD / 4) + (tid & 7)];
        float e  = (v.x + v.y) + (v.z + v.w);
#pragma unroll
        for (int off = 16; off >= 1; off >>= 1)
            e += __shfl_xor(e, off, 64);
        if (tid == 0) out[b] = mu_cur + __logf(e);
    }
}

extern "C" void kernel_launch(void* const* d_in, const int* in_sizes, int n_in,
                              void* d_out, int out_size, void* d_ws, size_t ws_size,
                              hipStream_t stream)
{
    const float* logits = (const float*)d_in[0];
    const float* trans  = (const float*)d_in[1];
    const int*   lens   = (const int*)d_in[2];
    float*       out    = (float*)d_out;

    const int B = in_sizes[2];                // lens element count
    const int S = in_sizes[0] / (B * L);      // logits = B*S*L

    crf_fwd_kernel<<<B, 512, 0, stream>>>(logits, trans, lens, out, S);
}